// Round 7
// baseline (552.036 us; speedup 1.0000x reference)
//
#include <hip/hip_runtime.h>
#include <float.h>

#define N_NODES_C 200000
#define HIDDEN_C 256
#define NSEG_C 1024
#define NEG_SLOPE_C 0.2f
#define NWAVE_C 8
#define SLOT_F 260   // floats per slot: {m, d, cnt, pad, acc[256]}

typedef float f32x4 __attribute__((ext_vector_type(4)));

__device__ __forceinline__ int lower_bound_dev(const int* __restrict__ b, int n, int v) {
    int lo = 0, hi = n;
    while (lo < hi) {
        int mid = (lo + hi) >> 1;
        if (b[mid] < v) lo = mid + 1; else hi = mid;
    }
    return lo;
}

// ---- Split-K: 2048 blocks, block b -> (segment b>>1, half b&1). ----
// 512 thr / 8 waves, 4 blocks/CU = 32 waves/CU; 2x oversubscription
// gives dynamic tail rebalancing. Last-done block per segment merges.
__global__ __launch_bounds__(512, 8)
void attn_split(const float* __restrict__ feature,
                const float* __restrict__ a,
                const int* __restrict__ batch,
                float* __restrict__ ws_slots,
                int* __restrict__ done,
                float* __restrict__ out) {
    const int b    = blockIdx.x;
    const int s    = b >> 1;
    const int p    = b & 1;
    const int tid  = threadIdx.x;
    const int lane = tid & 63;
    const int wid  = tid >> 6;

    __shared__ float part[NWAVE_C][HIDDEN_C];
    __shared__ float md[NWAVE_C][2];
    __shared__ int   oldret;

    const int s0  = lower_bound_dev(batch, N_NODES_C, s);
    const int s1  = lower_bound_dev(batch, N_NODES_C, s + 1);
    const int cnt = s1 - s0;
    const int half = cnt >> 1;
    const int p0  = p ? (s0 + half) : s0;
    const int p1  = p ? s1 : (s0 + half);

    const float4 av = *reinterpret_cast<const float4*>(a + 4 * lane);

    float m = -FLT_MAX;
    float d = 0.0f;
    f32x4 acc = {0.f, 0.f, 0.f, 0.f};

    auto ldrow = [&](int i) -> f32x4 {
        return __builtin_nontemporal_load(
            reinterpret_cast<const f32x4*>(feature + (size_t)i * HIDDEN_C + 4 * lane));
    };

    auto dotred = [&](const f32x4& f) -> float {
        float pr = f.x * av.x + f.y * av.y + f.z * av.z + f.w * av.w;
        #pragma unroll
        for (int off = 32; off >= 1; off >>= 1)
            pr += __shfl_xor(pr, off, 64);
        return (pr > 0.0f) ? pr : NEG_SLOPE_C * pr;
    };

    auto online = [&](float l, const f32x4& f) {
        if (l > m) {                      // wave-uniform branch
            const float sc = __expf(m - l);   // exp(-inf)=0 on first row
            acc.x = acc.x * sc + f.x;
            acc.y = acc.y * sc + f.y;
            acc.z = acc.z * sc + f.z;
            acc.w = acc.w * sc + f.w;
            d = d * sc + 1.0f;
            m = l;
        } else {
            const float w = __expf(l - m);
            acc.x += w * f.x;
            acc.y += w * f.y;
            acc.z += w * f.z;
            acc.w += w * f.w;
            d += w;
        }
    };

    // Depth-2 software pipeline over rows p0+wid :: 8.
    int i = p0 + wid;
    if (i + NWAVE_C < p1) {
        f32x4 f0 = ldrow(i);
        f32x4 f1 = ldrow(i + NWAVE_C);
        i += 2 * NWAVE_C;
        for (; i + NWAVE_C < p1; i += 2 * NWAVE_C) {
            const f32x4 n0 = ldrow(i);
            const f32x4 n1 = ldrow(i + NWAVE_C);
            const float l0 = dotred(f0);
            const float l1 = dotred(f1);
            online(l0, f0);
            online(l1, f1);
            f0 = n0; f1 = n1;
        }
        const float l0 = dotred(f0);
        const float l1 = dotred(f1);
        online(l0, f0);
        online(l1, f1);
    }
    if (i < p1) {
        const f32x4 f = ldrow(i);
        online(dotred(f), f);
    }

    // ---- Combine 8 wave partials -> unnormalized block partial. ----
    part[wid][4 * lane + 0] = acc.x;
    part[wid][4 * lane + 1] = acc.y;
    part[wid][4 * lane + 2] = acc.z;
    part[wid][4 * lane + 3] = acc.w;
    if (lane == 0) { md[wid][0] = m; md[wid][1] = d; }
    __syncthreads();

    float M = md[0][0];
    #pragma unroll
    for (int k = 1; k < NWAVE_C; ++k) M = fmaxf(M, md[k][0]);
    float D = 0.0f;
    #pragma unroll
    for (int k = 0; k < NWAVE_C; ++k) D += __expf(md[k][0] - M) * md[k][1];

    float* slot = ws_slots + (size_t)b * SLOT_F;
    if (tid < HIDDEN_C) {
        float v = 0.0f;
        #pragma unroll
        for (int k = 0; k < NWAVE_C; ++k)
            v += __expf(md[k][0] - M) * part[k][tid];
        slot[4 + tid] = v;
    }
    if (tid == 0) {
        slot[0] = M;
        slot[1] = D;
        slot[2] = (float)(p1 - p0);
    }
    __syncthreads();   // drains all slot stores (vmcnt(0) before barrier)

    // ---- Device-scope handshake: last block to finish this segment merges.
    if (tid == 0) {
        __threadfence();                       // release: writeback L2
        oldret = atomicAdd(&done[s], 1);
    }
    __syncthreads();

    if (oldret == 1) {
        __threadfence();                       // acquire: invalidate stale lines
        const float* sl0 = ws_slots + (size_t)(2 * s) * SLOT_F;
        const float* sl1 = sl0 + SLOT_F;
        const float m0 = sl0[0], d0 = sl0[1], c0 = sl0[2];
        const float m1 = sl1[0], d1 = sl1[1], c1 = sl1[2];
        const float Mm = fmaxf(m0, m1);
        const float e0 = __expf(m0 - Mm);      // empty half: exp(-inf)=0
        const float e1 = __expf(m1 - Mm);
        const float Dm = e0 * d0 + e1 * d1;
        const float cn = c0 + c1;
        if (tid < HIDDEN_C) {
            const float v = e0 * sl0[4 + tid] + e1 * sl1[4 + tid];
            out[(size_t)s * HIDDEN_C + tid] = (cn > 0.0f) ? v / (Dm * cn) : 0.0f;
        }
    }
}

// ---- Fallback: R6 single-kernel one-pass (proven 40.9 us). ----
__global__ __launch_bounds__(512, 8)
void attn_pool(const float* __restrict__ feature,
               const float* __restrict__ a,
               const int* __restrict__ batch,
               float* __restrict__ out) {
    const int s    = blockIdx.x;
    const int tid  = threadIdx.x;
    const int lane = tid & 63;
    const int wid  = tid >> 6;

    __shared__ float part[NWAVE_C][HIDDEN_C];
    __shared__ float md[NWAVE_C][2];

    const int s0  = lower_bound_dev(batch, N_NODES_C, s);
    const int s1  = lower_bound_dev(batch, N_NODES_C, s + 1);
    const int cnt = s1 - s0;

    if (cnt == 0) {
        if (tid < HIDDEN_C) out[(size_t)s * HIDDEN_C + tid] = 0.0f;
        return;
    }

    const float4 av = *reinterpret_cast<const float4*>(a + 4 * lane);

    float m = -FLT_MAX;
    float d = 0.0f;
    f32x4 acc = {0.f, 0.f, 0.f, 0.f};

    auto ldrow = [&](int i) -> f32x4 {
        return __builtin_nontemporal_load(
            reinterpret_cast<const f32x4*>(feature + (size_t)i * HIDDEN_C + 4 * lane));
    };

    auto dotred = [&](const f32x4& f) -> float {
        float pr = f.x * av.x + f.y * av.y + f.z * av.z + f.w * av.w;
        #pragma unroll
        for (int off = 32; off >= 1; off >>= 1)
            pr += __shfl_xor(pr, off, 64);
        return (pr > 0.0f) ? pr : NEG_SLOPE_C * pr;
    };

    auto online = [&](float l, const f32x4& f) {
        if (l > m) {
            const float sc = __expf(m - l);
            acc.x = acc.x * sc + f.x;
            acc.y = acc.y * sc + f.y;
            acc.z = acc.z * sc + f.z;
            acc.w = acc.w * sc + f.w;
            d = d * sc + 1.0f;
            m = l;
        } else {
            const float w = __expf(l - m);
            acc.x += w * f.x;
            acc.y += w * f.y;
            acc.z += w * f.z;
            acc.w += w * f.w;
            d += w;
        }
    };

    int i = s0 + wid;
    if (i + NWAVE_C < s1) {
        f32x4 f0 = ldrow(i);
        f32x4 f1 = ldrow(i + NWAVE_C);
        i += 2 * NWAVE_C;
        for (; i + NWAVE_C < s1; i += 2 * NWAVE_C) {
            const f32x4 n0 = ldrow(i);
            const f32x4 n1 = ldrow(i + NWAVE_C);
            const float l0 = dotred(f0);
            const float l1 = dotred(f1);
            online(l0, f0);
            online(l1, f1);
            f0 = n0; f1 = n1;
        }
        const float l0 = dotred(f0);
        const float l1 = dotred(f1);
        online(l0, f0);
        online(l1, f1);
    }
    if (i < s1) {
        const f32x4 f = ldrow(i);
        online(dotred(f), f);
    }

    part[wid][4 * lane + 0] = acc.x;
    part[wid][4 * lane + 1] = acc.y;
    part[wid][4 * lane + 2] = acc.z;
    part[wid][4 * lane + 3] = acc.w;
    if (lane == 0) { md[wid][0] = m; md[wid][1] = d; }
    __syncthreads();

    if (tid < HIDDEN_C) {
        float M = md[0][0];
        #pragma unroll
        for (int k = 1; k < NWAVE_C; ++k) M = fmaxf(M, md[k][0]);

        float D = 0.0f;
        float v = 0.0f;
        #pragma unroll
        for (int k = 0; k < NWAVE_C; ++k) {
            const float e = __expf(md[k][0] - M);
            D += e * md[k][1];
            v += e * part[k][tid];
        }
        out[(size_t)s * HIDDEN_C + tid] = v / (D * (float)cnt);
    }
}

extern "C" void kernel_launch(void* const* d_in, const int* in_sizes, int n_in,
                              void* d_out, int out_size, void* d_ws, size_t ws_size,
                              hipStream_t stream) {
    const float* feature = (const float*)d_in[0];
    const float* a       = (const float*)d_in[1];
    const int*   batch   = (const int*)d_in[2];
    float* out = (float*)d_out;
    (void)in_sizes; (void)n_in; (void)out_size;

    const size_t nSlots    = (size_t)NSEG_C * 2;                 // 2048
    const size_t slotBytes = nSlots * SLOT_F * sizeof(float);    // ~2.13 MB
    const size_t needed    = slotBytes + NSEG_C * sizeof(int);   // + done[1024]

    if (ws_size >= needed) {
        float* ws_slots = (float*)d_ws;
        int*   done     = (int*)((char*)d_ws + slotBytes);
        hipMemsetAsync(done, 0, NSEG_C * sizeof(int), stream);
        attn_split<<<(int)nSlots, 512, 0, stream>>>(feature, a, batch,
                                                    ws_slots, done, out);
    } else {
        attn_pool<<<NSEG_C, 512, 0, stream>>>(feature, a, batch, out);
    }
}

// Round 8
// 39.565 us; speedup vs baseline: 13.9528x; 13.9528x over previous
//
#include <hip/hip_runtime.h>
#include <float.h>

#define N_NODES_C 200000
#define HIDDEN_C 256
#define NSEG_C 1024
#define NEG_SLOPE_C 0.2f
#define NWAVE_C 8

typedef float f32x4 __attribute__((ext_vector_type(4)));

// One block per segment; 8 waves (512 thr) -> 4 blocks/CU = 32 waves/CU.
__global__ __launch_bounds__(512, 8)
void attn_pool(const float* __restrict__ feature,
               const float* __restrict__ a,
               const int* __restrict__ batch,
               float* __restrict__ out) {
    const int s    = blockIdx.x;
    const int tid  = threadIdx.x;
    const int lane = tid & 63;
    const int wid  = tid >> 6;          // 0..7

    __shared__ float part[NWAVE_C][HIDDEN_C];
    __shared__ float md[NWAVE_C][2];    // per-wave {max, denom}
    __shared__ int   sb[2];             // {s0, s1}

    // ---- Wave-parallel 3-phase probe search: 3 dependent loads, not 18.
    // Bracket narrowing 200000 -> 3125 -> 49 -> 1. Wave 0: lower_bound(s);
    // wave 1: lower_bound(s+1). Phase-3 width 64 covers the j=63 gap case.
    if (wid < 2) {
        const int target = s + wid;
        int lo = 0;
        int step = 3125;                 // ceil(200000/64)
        #pragma unroll
        for (int ph = 0; ph < 3; ++ph) {
            const int idx = lo + lane * step;
            const int v = (idx < N_NODES_C) ? batch[idx] : 0x7fffffff;
            const unsigned long long mask = __ballot(v < target);
            if (mask) lo += (63 - __builtin_clzll(mask)) * step + 1;
            step = (step == 3125) ? 49 : 1;
        }
        if (lane == 0) sb[wid] = lo;
    }
    __syncthreads();
    const int s0  = sb[0];
    const int s1  = sb[1];
    const int cnt = s1 - s0;

    if (cnt == 0) {
        if (tid < HIDDEN_C) out[(size_t)s * HIDDEN_C + tid] = 0.0f;
        return;
    }

    // Lane owns columns 4*lane .. 4*lane+3.
    const float4 av = *reinterpret_cast<const float4*>(a + 4 * lane);

    float m = -FLT_MAX;
    float d = 0.0f;
    f32x4 acc = {0.f, 0.f, 0.f, 0.f};

    // Non-temporal: feature is streamed exactly once, never reused.
    auto ldrow = [&](int i) -> f32x4 {
        return __builtin_nontemporal_load(
            reinterpret_cast<const f32x4*>(feature + (size_t)i * HIDDEN_C + 4 * lane));
    };

    auto dotred = [&](const f32x4& f) -> float {
        float p = f.x * av.x + f.y * av.y + f.z * av.z + f.w * av.w;
        #pragma unroll
        for (int off = 32; off >= 1; off >>= 1)
            p += __shfl_xor(p, off, 64);
        return (p > 0.0f) ? p : NEG_SLOPE_C * p;
    };

    auto online = [&](float l, const f32x4& f) {
        if (l > m) {                    // wave-uniform branch
            const float sc = __expf(m - l);   // exp(-inf)=0 on first row
            acc.x = acc.x * sc + f.x;
            acc.y = acc.y * sc + f.y;
            acc.z = acc.z * sc + f.z;
            acc.w = acc.w * sc + f.w;
            d = d * sc + 1.0f;
            m = l;
        } else {
            const float w = __expf(l - m);
            acc.x += w * f.x;
            acc.y += w * f.y;
            acc.z += w * f.z;
            acc.w += w * f.w;
            d += w;
        }
    };

    // Wave wid handles rows s0+wid :: 8. Depth-2 software pipeline.
    int i = s0 + wid;
    if (i + NWAVE_C < s1) {
        f32x4 f0 = ldrow(i);
        f32x4 f1 = ldrow(i + NWAVE_C);
        i += 2 * NWAVE_C;
        for (; i + NWAVE_C < s1; i += 2 * NWAVE_C) {
            const f32x4 nf0 = ldrow(i);
            const f32x4 nf1 = ldrow(i + NWAVE_C);
            const float l0 = dotred(f0);
            const float l1 = dotred(f1);
            online(l0, f0);
            online(l1, f1);
            f0 = nf0;
            f1 = nf1;
        }
        const float l0 = dotred(f0);
        const float l1 = dotred(f1);
        online(l0, f0);
        online(l1, f1);
    }
    if (i < s1) {
        const f32x4 f = ldrow(i);
        online(dotred(f), f);
    }

    // ---- Exact merge of the 8 wave partials. ----
    part[wid][4 * lane + 0] = acc.x;
    part[wid][4 * lane + 1] = acc.y;
    part[wid][4 * lane + 2] = acc.z;
    part[wid][4 * lane + 3] = acc.w;
    if (lane == 0) { md[wid][0] = m; md[wid][1] = d; }
    __syncthreads();

    if (tid < HIDDEN_C) {
        float M = md[0][0];
        #pragma unroll
        for (int k = 1; k < NWAVE_C; ++k) M = fmaxf(M, md[k][0]);

        float D = 0.0f;
        float v = 0.0f;
        #pragma unroll
        for (int k = 0; k < NWAVE_C; ++k) {
            const float e = __expf(md[k][0] - M);   // empty wave: exp(-inf)=0
            D += e * md[k][1];
            v += e * part[k][tid];
        }
        out[(size_t)s * HIDDEN_C + tid] = v / (D * (float)cnt);
    }
}

extern "C" void kernel_launch(void* const* d_in, const int* in_sizes, int n_in,
                              void* d_out, int out_size, void* d_ws, size_t ws_size,
                              hipStream_t stream) {
    const float* feature = (const float*)d_in[0];
    const float* a       = (const float*)d_in[1];
    const int*   batch   = (const int*)d_in[2];
    float* out = (float*)d_out;
    (void)in_sizes; (void)n_in; (void)out_size; (void)d_ws; (void)ws_size;

    attn_pool<<<NSEG_C, 512, 0, stream>>>(feature, a, batch, out);
}